// Round 7
// baseline (730.315 us; speedup 1.0000x reference)
//
#include <hip/hip_runtime.h>
#include <stdint.h>

// ---------------- constants ----------------
#define SEQ   2048
#define NH    16
#define DIMM  2048
#define QLR   768
#define KVLR  512
#define DN    128
#define DR    64
#define DV    128
#define QKH   192           // DN + DR
#define KVPAD 640           // 576 padded to multiple of 128
#define SCALE_F 0.07216878364870323f   // 192^-0.5
#define LAM_INIT 0.5560582f            // 0.8 - 0.6*exp(-0.9)
#define C1F      0.4439418f            // 1 - LAM_INIT
#define PSTR  36            // P_lds row stride (elements) — conflict-breaking pad
#define DTHR  8.0f          // defer-max threshold (T13)

// ---------------- types ----------------
typedef __attribute__((ext_vector_type(8))) uint16_t u16x8;
typedef __attribute__((ext_vector_type(8))) __bf16   bf16x8;
typedef __attribute__((ext_vector_type(4))) float    f32x4;

#define MFMA16(a,b,c) __builtin_amdgcn_mfma_f32_16x16x32_bf16((a),(b),(c),0,0,0)

__device__ __forceinline__ uint16_t f2bf(float f){ uint32_t x; __builtin_memcpy(&x,&f,4); return (uint16_t)((x + 0x7FFFu + ((x>>16)&1u))>>16); }
__device__ __forceinline__ float bfu(uint16_t u){ return (float)__builtin_bit_cast(__bf16, u); }
__device__ __forceinline__ bf16x8 ldfrag(const uint16_t* p){ return __builtin_bit_cast(bf16x8, *(const u16x8*)p); }
__device__ __forceinline__ void gload_lds16(const uint16_t* g, uint16_t* l){
  __builtin_amdgcn_global_load_lds((const __attribute__((address_space(1))) void*)g,
                                   (__attribute__((address_space(3))) void*)l, 16, 0, 0);
}
__device__ __forceinline__ void stor(uint16_t* p, float v){ *p = f2bf(v); }
__device__ __forceinline__ void stor(float* p, float v){ *p = v; }

// ---------------- f32 -> bf16 converters ----------------
__global__ void cvt(const float* __restrict__ in, uint16_t* __restrict__ outp){
  int i = (blockIdx.x*256 + threadIdx.x)*8;
  float4 a = *(const float4*)(in + i);
  float4 b = *(const float4*)(in + i + 4);
  u16x8 r;
  r[0]=f2bf(a.x); r[1]=f2bf(a.y); r[2]=f2bf(a.z); r[3]=f2bf(a.w);
  r[4]=f2bf(b.x); r[5]=f2bf(b.y); r[6]=f2bf(b.z); r[7]=f2bf(b.w);
  *(u16x8*)(outp + i) = r;
}

// wkv_a f32 [576][2048] -> bf16 [640][2048] zero-padded
__global__ void pad_wkva(const float* __restrict__ in, uint16_t* __restrict__ outp){
  int idx = blockIdx.x*256 + threadIdx.x;          // KVPAD*DIMM
  int n = idx >> 11;
  outp[idx] = (n < 576) ? f2bf(in[idx]) : (uint16_t)0;
}

// ---------------- GEMM: C[M][N] = A[M][K] (lda) * B[N][K]^T, bf16 in, f32 acc ----
// 128x128 tile, 4 waves (2x2 of 64x64), BK=32, global_load_lds staging.
template <typename OT>
__global__ __launch_bounds__(256) void gemm_bt(const uint16_t* __restrict__ A, int lda,
                                               const uint16_t* __restrict__ B,
                                               OT* __restrict__ C, int ldc, int K)
{
  __shared__ __align__(16) uint16_t As[128*32];
  __shared__ __align__(16) uint16_t Bs[128*32];
  const int tid  = threadIdx.x;
  const int wid  = tid >> 6;
  const int lane = tid & 63;
  const int wr   = (wid >> 1) * 64;
  const int wc   = (wid & 1) * 64;
  const int srow = lane >> 2;
  const int scol = (lane & 3) * 8;
  const uint16_t* Abase = A + (size_t)(blockIdx.x * 128) * lda;
  const uint16_t* Bbase = B + (size_t)(blockIdx.y * 128) * K;
  f32x4 acc[4][4] = {};
  for (int k0 = 0; k0 < K; k0 += 32) {
    __syncthreads();
#pragma unroll
    for (int c = 0; c < 2; ++c) {
      int r = (wid*2 + c)*16 + srow;
      gload_lds16(Abase + (size_t)r*lda + k0 + scol, &As[(wid*2 + c)*512]);
      gload_lds16(Bbase + (size_t)r*K   + k0 + scol, &Bs[(wid*2 + c)*512]);
    }
    __syncthreads();
    bf16x8 af[4], bfr[4];
#pragma unroll
    for (int m = 0; m < 4; ++m)
      af[m] = ldfrag(&As[(wr + m*16 + (lane&15))*32 + ((lane>>4)*8)]);
#pragma unroll
    for (int n = 0; n < 4; ++n)
      bfr[n] = ldfrag(&Bs[(wc + n*16 + (lane&15))*32 + ((lane>>4)*8)]);
#pragma unroll
    for (int m = 0; m < 4; ++m)
#pragma unroll
      for (int n = 0; n < 4; ++n)
        acc[m][n] = MFMA16(af[m], bfr[n], acc[m][n]);
  }
  const int rbase = blockIdx.x*128 + wr + ((lane>>4)<<2);
  const int cbase = blockIdx.y*128 + wc + (lane&15);
#pragma unroll
  for (int m = 0; m < 4; ++m)
#pragma unroll
    for (int n = 0; n < 4; ++n)
#pragma unroll
      for (int r = 0; r < 4; ++r)
        stor(&C[(size_t)(rbase + m*16 + r)*ldc + cbase + n*16], acc[m][n][r]);
}

// ---- kvb GEMM with fused scatter epilogue: writes k_nope into kfull and V into vtb^T
__global__ __launch_bounds__(256) void gemm_kvb(const uint16_t* __restrict__ A, int lda,
                                                const uint16_t* __restrict__ B,
                                                uint16_t* __restrict__ kfull,
                                                uint16_t* __restrict__ vtb, int K)
{
  __shared__ __align__(16) uint16_t As[128*32];
  __shared__ __align__(16) uint16_t Bs[128*32];
  const int tid  = threadIdx.x;
  const int wid  = tid >> 6;
  const int lane = tid & 63;
  const int wr   = (wid >> 1) * 64;
  const int wc   = (wid & 1) * 64;
  const int srow = lane >> 2;
  const int scol = (lane & 3) * 8;
  const uint16_t* Abase = A + (size_t)(blockIdx.x * 128) * lda;
  const uint16_t* Bbase = B + (size_t)(blockIdx.y * 128) * K;
  f32x4 acc[4][4] = {};
  for (int k0 = 0; k0 < K; k0 += 32) {
    __syncthreads();
#pragma unroll
    for (int c = 0; c < 2; ++c) {
      int r = (wid*2 + c)*16 + srow;
      gload_lds16(Abase + (size_t)r*lda + k0 + scol, &As[(wid*2 + c)*512]);
      gload_lds16(Bbase + (size_t)r*K   + k0 + scol, &Bs[(wid*2 + c)*512]);
    }
    __syncthreads();
    bf16x8 af[4], bfr[4];
#pragma unroll
    for (int m = 0; m < 4; ++m)
      af[m] = ldfrag(&As[(wr + m*16 + (lane&15))*32 + ((lane>>4)*8)]);
#pragma unroll
    for (int n = 0; n < 4; ++n)
      bfr[n] = ldfrag(&Bs[(wc + n*16 + (lane&15))*32 + ((lane>>4)*8)]);
#pragma unroll
    for (int m = 0; m < 4; ++m)
#pragma unroll
      for (int n = 0; n < 4; ++n)
        acc[m][n] = MFMA16(af[m], bfr[n], acc[m][n]);
  }
  const int rbase = blockIdx.x*128 + wr + ((lane>>4)<<2);
  const int cbase = blockIdx.y*128 + wc + (lane&15);
#pragma unroll
  for (int m = 0; m < 4; ++m)
#pragma unroll
    for (int n = 0; n < 4; ++n) {
      const int gcol = cbase + n*16;
      const int hh = gcol >> 8, d = gcol & 255;
#pragma unroll
      for (int r = 0; r < 4; ++r) {
        const int t = rbase + m*16 + r;
        if (d < DN) kfull[((size_t)hh*SEQ + t)*QKH + d] = f2bf(acc[m][n][r]);
        else        vtb[((size_t)hh*DV + (d - DN))*SEQ + t] = f2bf(acc[m][n][r]);
      }
    }
}

// ---------------- small kernels ----------------
__global__ void lam_kernel(const float* lqn, const float* lqr,
                           const float* lkn, const float* lkr, float* outp){
  if (threadIdx.x == 0 && blockIdx.x == 0) {
    float d1 = 0.f, d2 = 0.f;
    for (int i = 0; i < DN; ++i) d1 += lqn[i] * lkn[i];
    for (int i = 0; i < DR; ++i) d2 += lqr[i] * lkr[i];
    outp[0] = __expf(d1) - __expf(d2) + LAM_INIT;
  }
}

__global__ void rope_q(uint16_t* __restrict__ q, const float* __restrict__ cs,
                       const float* __restrict__ sn){
  int idx = blockIdx.x*256 + threadIdx.x;          // SEQ*NH*32
  int j = idx & 31, hh = (idx>>5) & 15, s = idx >> 9;
  uint16_t* p = q + (size_t)s*(NH*QKH) + hh*QKH + DN + 2*j;
  float xr = bfu(p[0]), xi = bfu(p[1]);
  float c = cs[s*32+j], si = sn[s*32+j];
  p[0] = f2bf(xr*c - xi*si);
  p[1] = f2bf(xr*si + xi*c);
}

// rope'd k_pe -> kfull[h][t][128..192)
__global__ void rope_k(const uint16_t* __restrict__ kvf, const float* __restrict__ cs,
                       const float* __restrict__ sn, uint16_t* __restrict__ kfull){
  int idx = blockIdx.x*256 + threadIdx.x;          // NH*SEQ*32
  int j = idx & 31, t = (idx>>5) & 2047, hh = idx >> 16;
  float xr = bfu(kvf[(size_t)t*KVPAD + KVLR + 2*j]);
  float xi = bfu(kvf[(size_t)t*KVPAD + KVLR + 2*j + 1]);
  float c = cs[t*32+j], si = sn[t*32+j];
  uint16_t* p = kfull + ((size_t)hh*SEQ + t)*QKH + DN + 2*j;
  p[0] = f2bf(xr*c - xi*si);
  p[1] = f2bf(xr*si + xi*c);
}

// ---------------- attention ----------------
// Block = (q-chunk of 16 rows, head), 4 waves. Waves split the kv-tile range
// (wave w takes tiles i ≡ w mod 4), each with private (m,l,O1,O2); partials
// tree-combined through LDS at the end (exact online-softmax merge).
__global__ __launch_bounds__(256) __attribute__((amdgpu_waves_per_eu(4)))
void attn_kernel(
    const uint16_t* __restrict__ q,     // [SEQ][NH*QKH]
    const uint16_t* __restrict__ kf,    // [NH][SEQ][QKH]
    const uint16_t* __restrict__ vt,    // [NH][DV][SEQ]
    const float* __restrict__ lamp,
    uint16_t* __restrict__ o)           // [SEQ][NH*DV]
{
  __shared__ __align__(16) uint16_t P_lds[4][4][16*PSTR];   // [wave][slice]
  __shared__ float R_lds[2][64*41];                          // combine buffers
  const int b  = blockIdx.x;
  const int h  = b & 15;
  const int c  = b >> 4;               // 0..127
  const int wid  = threadIdx.x >> 6;
  const int lane = threadIdx.x & 63;
  const int l15 = lane & 15;
  const int lhi = lane >> 4;
  const int subrow = lhi * 4;
  const int qrow0 = c * 16;
  const int kend  = qrow0 + 16;        // causal kv extent
  const float lam = lamp[0];

  bf16x8 qf[6];
  {
    const uint16_t* qbase = q + (size_t)(qrow0 + l15)*(NH*QKH) + h*QKH + lhi*8;
#pragma unroll
    for (int kb = 0; kb < 6; ++kb) qf[kb] = ldfrag(qbase + kb*32);
  }
  f32x4 O1[8] = {}, O2[8] = {};
  float m1[4], m2[4], l1[4], l2[4];
#pragma unroll
  for (int r = 0; r < 4; ++r) { m1[r] = m2[r] = -1e30f; l1[r] = l2[r] = 0.f; }

  const uint16_t* kbase = kf + (size_t)h*SEQ*QKH;
  const uint16_t* vbase = vt + (size_t)h*DV*SEQ;

  auto loadK = [&](bf16x8 (&k0)[6], bf16x8 (&k1)[6], int t0){
    const uint16_t* kp0 = kbase + (size_t)(t0 + l15)*QKH + lhi*8;
    const uint16_t* kp1 = kp0 + (size_t)16*QKH;
#pragma unroll
    for (int kb = 0; kb < 6; ++kb) { k0[kb] = ldfrag(kp0 + kb*32); k1[kb] = ldfrag(kp1 + kb*32); }
  };
  auto loadV = [&](bf16x8 (&vf)[8], int t0){
#pragma unroll
    for (int n = 0; n < 8; ++n) vf[n] = ldfrag(vbase + (size_t)(n*16 + l15)*SEQ + t0 + lhi*8);
  };
  auto qk = [&](bf16x8 (&k0)[6], bf16x8 (&k1)[6], f32x4 (&s1)[2], f32x4 (&s2)[2]){
    __builtin_amdgcn_s_setprio(1);
#pragma unroll
    for (int kb = 0; kb < 3; ++kb) { s1[0] = MFMA16(qf[kb], k0[kb], s1[0]); s1[1] = MFMA16(qf[kb], k1[kb], s1[1]); }
#pragma unroll
    for (int kb = 3; kb < 6; ++kb) { s2[0] = MFMA16(qf[kb], k0[kb], s2[0]); s2[1] = MFMA16(qf[kb], k1[kb], s2[1]); }
    __builtin_amdgcn_s_setprio(0);
  };
  auto smax = [&](f32x4 (&s1)[2], f32x4 (&s2)[2], int t0, bool MASKED,
                  uint16_t* pa, uint16_t* pb){
#pragma unroll
    for (int half = 0; half < 2; ++half)
#pragma unroll
      for (int r = 0; r < 4; ++r) {
        float v1 = fminf(fmaxf(s1[half][r]*SCALE_F, -100.f), 100.f);
        float v2 = fminf(fmaxf(s2[half][r]*SCALE_F, -100.f), 100.f);
        if (MASKED && (t0 + half*16 + l15 > qrow0 + subrow + r)) { v1 = -1e30f; v2 = -1e30f; }
        s1[half][r] = v1; s2[half][r] = v2;
      }
    float t1[4], t2[4];
#pragma unroll
    for (int r = 0; r < 4; ++r) { t1[r] = fmaxf(s1[0][r], s1[1][r]); t2[r] = fmaxf(s2[0][r], s2[1][r]); }
#pragma unroll
    for (int off = 1; off < 16; off <<= 1)
#pragma unroll
      for (int r = 0; r < 4; ++r) {
        t1[r] = fmaxf(t1[r], __shfl_xor(t1[r], off, 64));
        t2[r] = fmaxf(t2[r], __shfl_xor(t2[r], off, 64));
      }
    bool ok1 = (t1[0] <= m1[0]+DTHR) && (t1[1] <= m1[1]+DTHR) && (t1[2] <= m1[2]+DTHR) && (t1[3] <= m1[3]+DTHR);
    if (!__all(ok1)) {
#pragma unroll
      for (int r = 0; r < 4; ++r) {
        float mn = fmaxf(m1[r], t1[r]);
        float cr = __expf(m1[r] - mn);
        m1[r] = mn; l1[r] *= cr;
#pragma unroll
        for (int n = 0; n < 8; ++n) O1[n][r] *= cr;
      }
    }
    bool ok2 = (t2[0] <= m2[0]+DTHR) && (t2[1] <= m2[1]+DTHR) && (t2[2] <= m2[2]+DTHR) && (t2[3] <= m2[3]+DTHR);
    if (!__all(ok2)) {
#pragma unroll
      for (int r = 0; r < 4; ++r) {
        float mn = fmaxf(m2[r], t2[r]);
        float cr = __expf(m2[r] - mn);
        m2[r] = mn; l2[r] *= cr;
#pragma unroll
        for (int n = 0; n < 8; ++n) O2[n][r] *= cr;
      }
    }
    float rs1[4], rs2[4];
#pragma unroll
    for (int r = 0; r < 4; ++r) {
      float p10 = __expf(s1[0][r] - m1[r]), p11 = __expf(s1[1][r] - m1[r]);
      float p20 = __expf(s2[0][r] - m2[r]), p21 = __expf(s2[1][r] - m2[r]);
      pa[(subrow + r)*PSTR +      l15] = f2bf(p10);
      pa[(subrow + r)*PSTR + 16 + l15] = f2bf(p11);
      pb[(subrow + r)*PSTR +      l15] = f2bf(p20);
      pb[(subrow + r)*PSTR + 16 + l15] = f2bf(p21);
      rs1[r] = p10 + p11; rs2[r] = p20 + p21;
    }
#pragma unroll
    for (int off = 1; off < 16; off <<= 1)
#pragma unroll
      for (int r = 0; r < 4; ++r) {
        rs1[r] += __shfl_xor(rs1[r], off, 64);
        rs2[r] += __shfl_xor(rs2[r], off, 64);
      }
#pragma unroll
    for (int r = 0; r < 4; ++r) { l1[r] += rs1[r]; l2[r] += rs2[r]; }
  };
  auto pv = [&](bf16x8 (&vf)[8], const uint16_t* pa, const uint16_t* pb){
    bf16x8 pf0 = ldfrag(&pa[l15*PSTR + lhi*8]);
    bf16x8 pf1 = ldfrag(&pb[l15*PSTR + lhi*8]);
    __builtin_amdgcn_s_setprio(1);
#pragma unroll
    for (int n = 0; n < 8; ++n) {
      O1[n] = MFMA16(pf0, vf[n], O1[n]);
      O2[n] = MFMA16(pf1, vf[n], O2[n]);
    }
    __builtin_amdgcn_s_setprio(0);
  };

  uint16_t* plA0 = &P_lds[wid][0][0]; uint16_t* plA1 = &P_lds[wid][1][0];
  uint16_t* plB0 = &P_lds[wid][2][0]; uint16_t* plB1 = &P_lds[wid][3][0];

  const int n_tiles = (kend + 31) >> 5;
  const int nm = n_tiles - 1;          // index of the masked (diagonal) tile

  bf16x8 kr0[6], kr1[6], vfa[8], vfb[8];
  // paired unmasked tiles for this wave (indices wid, wid+4, ...)
  int i = wid;
  for (; i + 4 < nm; i += 8) {
    const int ta = i*32, tb = (i+4)*32;
    loadK(kr0, kr1, ta);
    loadV(vfa, ta);
    f32x4 sA1[2] = {}, sA2[2] = {};
    qk(kr0, kr1, sA1, sA2);
    loadK(kr0, kr1, tb);
    smax(sA1, sA2, ta, false, plA0, plA1);
    f32x4 sB1[2] = {}, sB2[2] = {};
    qk(kr0, kr1, sB1, sB2);
    loadV(vfb, tb);
    smax(sB1, sB2, tb, false, plB0, plB1);
    asm volatile("s_waitcnt lgkmcnt(0)" ::: "memory");
    __builtin_amdgcn_sched_barrier(0);
    pv(vfa, plA0, plA1);
    pv(vfb, plB0, plB1);
  }
  if (i < nm) {
    loadK(kr0, kr1, i*32);
    loadV(vfa, i*32);
    f32x4 s1[2] = {}, s2[2] = {};
    qk(kr0, kr1, s1, s2);
    smax(s1, s2, i*32, false, plA0, plA1);
    asm volatile("s_waitcnt lgkmcnt(0)" ::: "memory");
    __builtin_amdgcn_sched_barrier(0);
    pv(vfa, plA0, plA1);
  }
  if ((nm & 3) == wid) {
    loadK(kr0, kr1, nm*32);
    loadV(vfa, nm*32);
    f32x4 s1[2] = {}, s2[2] = {};
    qk(kr0, kr1, s1, s2);
    smax(s1, s2, nm*32, true, plA0, plA1);
    asm volatile("s_waitcnt lgkmcnt(0)" ::: "memory");
    __builtin_amdgcn_sched_barrier(0);
    pv(vfa, plA0, plA1);
  }

  // ---- cross-wave combine (exact online-softmax merge), tree: (2,3)->(0,1)->(0)
  auto write_state = [&](float* buf, const float* mm, const float* ll, const f32x4* O){
    float* p = buf + lane*41;
#pragma unroll
    for (int r = 0; r < 4; ++r) { p[r] = mm[r]; p[4+r] = ll[r]; }
#pragma unroll
    for (int n = 0; n < 8; ++n)
#pragma unroll
      for (int r = 0; r < 4; ++r) p[8 + n*4 + r] = O[n][r];
  };
  auto merge_state = [&](const float* buf, float* mm, float* ll, f32x4* O){
    const float* p = buf + lane*41;
    float ca[4], cb[4];
#pragma unroll
    for (int r = 0; r < 4; ++r) {
      float mo = p[r], lo = p[4+r];
      float mn = fmaxf(mm[r], mo);
      ca[r] = __expf(mm[r] - mn); cb[r] = __expf(mo - mn);
      mm[r] = mn; ll[r] = ll[r]*ca[r] + lo*cb[r];
    }
#pragma unroll
    for (int n = 0; n < 8; ++n)
#pragma unroll
      for (int r = 0; r < 4; ++r) O[n][r] = O[n][r]*ca[r] + p[8 + n*4 + r]*cb[r];
  };

  if (wid >= 2) write_state(R_lds[wid-2], m1, l1, O1);
  __syncthreads();
  if (wid < 2)  merge_state(R_lds[wid], m1, l1, O1);
  __syncthreads();
  if (wid >= 2) write_state(R_lds[wid-2], m2, l2, O2);
  __syncthreads();
  if (wid < 2)  merge_state(R_lds[wid], m2, l2, O2);
  __syncthreads();
  if (wid == 1) { write_state(R_lds[0], m1, l1, O1); write_state(R_lds[1], m2, l2, O2); }
  __syncthreads();
  if (wid == 0) {
    merge_state(R_lds[0], m1, l1, O1);
    merge_state(R_lds[1], m2, l2, O2);
    // epilogue: (O1/l1 - lam*O2/l2) * (1-lambda_init)
#pragma unroll
    for (int r = 0; r < 4; ++r) {
      float inv1 = 1.f / l1[r], inv2 = lam / l2[r];
#pragma unroll
      for (int n = 0; n < 8; ++n) {
        float val = (O1[n][r]*inv1 - O2[n][r]*inv2) * C1F;
        o[(size_t)(qrow0 + subrow + r)*(NH*DV) + h*DV + n*16 + l15] = f2bf(val);
      }
    }
  }
}

// ---------------- launch ----------------
extern "C" void kernel_launch(void* const* d_in, const int* in_sizes, int n_in,
                              void* d_out, int out_size, void* d_ws, size_t ws_size,
                              hipStream_t stream)
{
  const float* x     = (const float*)d_in[0];
  const float* wq_a  = (const float*)d_in[1];
  const float* wq_b  = (const float*)d_in[2];
  const float* wkv_a = (const float*)d_in[3];
  const float* wkv_b = (const float*)d_in[4];
  const float* wo    = (const float*)d_in[5];
  const float* lqn   = (const float*)d_in[6];
  const float* lqr   = (const float*)d_in[7];
  const float* lkn   = (const float*)d_in[8];
  const float* lkr   = (const float*)d_in[9];
  const float* fcos  = (const float*)d_in[10];
  const float* fsin  = (const float*)d_in[11];

  char* ws = (char*)d_ws;
  size_t off = 0;
  float*    lam    = (float*)(ws + off);  off += 256;
  uint16_t* xb     = (uint16_t*)(ws + off); off += (size_t)DIMM*DIMM*2;
  uint16_t* wqab   = (uint16_t*)(ws + off); off += (size_t)QLR*DIMM*2;
  uint16_t* wqbb   = (uint16_t*)(ws + off); off += (size_t)NH*QKH*QLR*2;
  uint16_t* wkvap  = (uint16_t*)(ws + off); off += (size_t)KVPAD*DIMM*2;
  uint16_t* wkvbb  = (uint16_t*)(ws + off); off += (size_t)4096*KVLR*2;
  uint16_t* wob    = (uint16_t*)(ws + off); off += (size_t)DIMM*DIMM*2;
  uint16_t* qlat   = (uint16_t*)(ws + off); off += (size_t)SEQ*QLR*2;
  uint16_t* qbuf   = (uint16_t*)(ws + off); off += (size_t)SEQ*NH*QKH*2;
  uint16_t* kvfull = (uint16_t*)(ws + off); off += (size_t)SEQ*KVPAD*2;
  uint16_t* kfull  = (uint16_t*)(ws + off); off += (size_t)NH*SEQ*QKH*2;
  uint16_t* vtb    = (uint16_t*)(ws + off); off += (size_t)NH*DV*SEQ*2;
  uint16_t* attn   = (uint16_t*)(ws + off); off += (size_t)SEQ*NH*DV*2;

  lam_kernel<<<1, 64, 0, stream>>>(lqn, lqr, lkn, lkr, lam);
  cvt<<<2048, 256, 0, stream>>>(x, xb);
  cvt<<< 768, 256, 0, stream>>>(wq_a, wqab);
  cvt<<<1152, 256, 0, stream>>>(wq_b, wqbb);
  cvt<<<1024, 256, 0, stream>>>(wkv_b, wkvbb);
  cvt<<<2048, 256, 0, stream>>>(wo, wob);
  pad_wkva<<<5120, 256, 0, stream>>>(wkv_a, wkvap);

  // q_lat = x @ wq_a^T
  gemm_bt<<<dim3(16, 6), 256, 0, stream>>>(xb, DIMM, wqab, qlat, QLR, DIMM);
  // q = q_lat @ wq_b^T
  gemm_bt<<<dim3(16, 24), 256, 0, stream>>>(qlat, QLR, wqbb, qbuf, NH*QKH, QLR);
  rope_q<<<4096, 256, 0, stream>>>(qbuf, fcos, fsin);
  // kv_full = x @ wkv_a_pad^T
  gemm_bt<<<dim3(16, 5), 256, 0, stream>>>(xb, DIMM, wkvap, kvfull, KVPAD, DIMM);
  // kvb GEMM fused: k_nope -> kfull, V -> vtb^T
  gemm_kvb<<<dim3(16, 32), 256, 0, stream>>>(kvfull, KVPAD, wkvbb, kfull, vtb, KVLR);
  rope_k<<<4096, 256, 0, stream>>>(kvfull, fcos, fsin, kfull);
  attn_kernel<<<2048, 256, 0, stream>>>(qbuf, kfull, vtb, lam, attn);
  // out = attn_out @ wo^T  (f32 output)
  gemm_bt<<<dim3(16, 16), 256, 0, stream>>>(attn, NH*DV, wob, (float*)d_out, DIMM, DIMM);
}

// Round 8
// 712.550 us; speedup vs baseline: 1.0249x; 1.0249x over previous
//
#include <hip/hip_runtime.h>
#include <stdint.h>

// ---------------- constants ----------------
#define SEQ   2048
#define NH    16
#define DIMM  2048
#define QLR   768
#define KVLR  512
#define DN    128
#define DR    64
#define DV    128
#define QKH   192           // DN + DR
#define KVPAD 640           // 576 padded to multiple of 128
#define SCALE_F 0.07216878364870323f   // 192^-0.5
#define LAM_INIT 0.5560582f            // 0.8 - 0.6*exp(-0.9)
#define C1F      0.4439418f            // 1 - LAM_INIT
#define PSTR  36            // P_lds row stride (elements) — conflict-breaking pad
#define DTHR  8.0f          // defer-max threshold (T13)

// ---------------- types ----------------
typedef __attribute__((ext_vector_type(8))) uint16_t u16x8;
typedef __attribute__((ext_vector_type(8))) __bf16   bf16x8;
typedef __attribute__((ext_vector_type(4))) float    f32x4;

#define MFMA16(a,b,c) __builtin_amdgcn_mfma_f32_16x16x32_bf16((a),(b),(c),0,0,0)

__device__ __forceinline__ uint16_t f2bf(float f){ uint32_t x; __builtin_memcpy(&x,&f,4); return (uint16_t)((x + 0x7FFFu + ((x>>16)&1u))>>16); }
__device__ __forceinline__ float bfu(uint16_t u){ return (float)__builtin_bit_cast(__bf16, u); }
__device__ __forceinline__ bf16x8 ldfrag(const uint16_t* p){ return __builtin_bit_cast(bf16x8, *(const u16x8*)p); }
__device__ __forceinline__ void gload_lds16(const uint16_t* g, uint16_t* l){
  __builtin_amdgcn_global_load_lds((const __attribute__((address_space(1))) void*)g,
                                   (__attribute__((address_space(3))) void*)l, 16, 0, 0);
}
__device__ __forceinline__ void stor(uint16_t* p, float v){ *p = f2bf(v); }
__device__ __forceinline__ void stor(float* p, float v){ *p = v; }

// ---------------- f32 -> bf16 converters ----------------
__global__ void cvt(const float* __restrict__ in, uint16_t* __restrict__ outp){
  int i = (blockIdx.x*256 + threadIdx.x)*8;
  float4 a = *(const float4*)(in + i);
  float4 b = *(const float4*)(in + i + 4);
  u16x8 r;
  r[0]=f2bf(a.x); r[1]=f2bf(a.y); r[2]=f2bf(a.z); r[3]=f2bf(a.w);
  r[4]=f2bf(b.x); r[5]=f2bf(b.y); r[6]=f2bf(b.z); r[7]=f2bf(b.w);
  *(u16x8*)(outp + i) = r;
}

// wkv_a f32 [576][2048] -> bf16 [640][2048] zero-padded
__global__ void pad_wkva(const float* __restrict__ in, uint16_t* __restrict__ outp){
  int idx = blockIdx.x*256 + threadIdx.x;          // KVPAD*DIMM
  int n = idx >> 11;
  outp[idx] = (n < 576) ? f2bf(in[idx]) : (uint16_t)0;
}

// ---------------- GEMM: C[M][N] = A[M][K] (lda) * B[N][K]^T, bf16 in, f32 acc ----
// 128x128 tile, 4 waves (2x2 of 64x64), BK=32, global_load_lds staging.
template <typename OT>
__global__ __launch_bounds__(256) void gemm_bt(const uint16_t* __restrict__ A, int lda,
                                               const uint16_t* __restrict__ B,
                                               OT* __restrict__ C, int ldc, int K)
{
  __shared__ __align__(16) uint16_t As[128*32];
  __shared__ __align__(16) uint16_t Bs[128*32];
  const int tid  = threadIdx.x;
  const int wid  = tid >> 6;
  const int lane = tid & 63;
  const int wr   = (wid >> 1) * 64;
  const int wc   = (wid & 1) * 64;
  const int srow = lane >> 2;
  const int scol = (lane & 3) * 8;
  const uint16_t* Abase = A + (size_t)(blockIdx.x * 128) * lda;
  const uint16_t* Bbase = B + (size_t)(blockIdx.y * 128) * K;
  f32x4 acc[4][4] = {};
  for (int k0 = 0; k0 < K; k0 += 32) {
    __syncthreads();
#pragma unroll
    for (int c = 0; c < 2; ++c) {
      int r = (wid*2 + c)*16 + srow;
      gload_lds16(Abase + (size_t)r*lda + k0 + scol, &As[(wid*2 + c)*512]);
      gload_lds16(Bbase + (size_t)r*K   + k0 + scol, &Bs[(wid*2 + c)*512]);
    }
    __syncthreads();
    bf16x8 af[4], bfr[4];
#pragma unroll
    for (int m = 0; m < 4; ++m)
      af[m] = ldfrag(&As[(wr + m*16 + (lane&15))*32 + ((lane>>4)*8)]);
#pragma unroll
    for (int n = 0; n < 4; ++n)
      bfr[n] = ldfrag(&Bs[(wc + n*16 + (lane&15))*32 + ((lane>>4)*8)]);
#pragma unroll
    for (int m = 0; m < 4; ++m)
#pragma unroll
      for (int n = 0; n < 4; ++n)
        acc[m][n] = MFMA16(af[m], bfr[n], acc[m][n]);
  }
  const int rbase = blockIdx.x*128 + wr + ((lane>>4)<<2);
  const int cbase = blockIdx.y*128 + wc + (lane&15);
#pragma unroll
  for (int m = 0; m < 4; ++m)
#pragma unroll
    for (int n = 0; n < 4; ++n)
#pragma unroll
      for (int r = 0; r < 4; ++r)
        stor(&C[(size_t)(rbase + m*16 + r)*ldc + cbase + n*16], acc[m][n][r]);
}

// ---- kvb GEMM with fused scatter epilogue: writes k_nope into kfull and V into vtb^T
__global__ __launch_bounds__(256) void gemm_kvb(const uint16_t* __restrict__ A, int lda,
                                                const uint16_t* __restrict__ B,
                                                uint16_t* __restrict__ kfull,
                                                uint16_t* __restrict__ vtb, int K)
{
  __shared__ __align__(16) uint16_t As[128*32];
  __shared__ __align__(16) uint16_t Bs[128*32];
  const int tid  = threadIdx.x;
  const int wid  = tid >> 6;
  const int lane = tid & 63;
  const int wr   = (wid >> 1) * 64;
  const int wc   = (wid & 1) * 64;
  const int srow = lane >> 2;
  const int scol = (lane & 3) * 8;
  const uint16_t* Abase = A + (size_t)(blockIdx.x * 128) * lda;
  const uint16_t* Bbase = B + (size_t)(blockIdx.y * 128) * K;
  f32x4 acc[4][4] = {};
  for (int k0 = 0; k0 < K; k0 += 32) {
    __syncthreads();
#pragma unroll
    for (int c = 0; c < 2; ++c) {
      int r = (wid*2 + c)*16 + srow;
      gload_lds16(Abase + (size_t)r*lda + k0 + scol, &As[(wid*2 + c)*512]);
      gload_lds16(Bbase + (size_t)r*K   + k0 + scol, &Bs[(wid*2 + c)*512]);
    }
    __syncthreads();
    bf16x8 af[4], bfr[4];
#pragma unroll
    for (int m = 0; m < 4; ++m)
      af[m] = ldfrag(&As[(wr + m*16 + (lane&15))*32 + ((lane>>4)*8)]);
#pragma unroll
    for (int n = 0; n < 4; ++n)
      bfr[n] = ldfrag(&Bs[(wc + n*16 + (lane&15))*32 + ((lane>>4)*8)]);
#pragma unroll
    for (int m = 0; m < 4; ++m)
#pragma unroll
      for (int n = 0; n < 4; ++n)
        acc[m][n] = MFMA16(af[m], bfr[n], acc[m][n]);
  }
  const int rbase = blockIdx.x*128 + wr + ((lane>>4)<<2);
  const int cbase = blockIdx.y*128 + wc + (lane&15);
#pragma unroll
  for (int m = 0; m < 4; ++m)
#pragma unroll
    for (int n = 0; n < 4; ++n) {
      const int gcol = cbase + n*16;
      const int hh = gcol >> 8, d = gcol & 255;
#pragma unroll
      for (int r = 0; r < 4; ++r) {
        const int t = rbase + m*16 + r;
        if (d < DN) kfull[((size_t)hh*SEQ + t)*QKH + d] = f2bf(acc[m][n][r]);
        else        vtb[((size_t)hh*DV + (d - DN))*SEQ + t] = f2bf(acc[m][n][r]);
      }
    }
}

// ---------------- small kernels ----------------
__global__ void lam_kernel(const float* lqn, const float* lqr,
                           const float* lkn, const float* lkr, float* outp){
  if (threadIdx.x == 0 && blockIdx.x == 0) {
    float d1 = 0.f, d2 = 0.f;
    for (int i = 0; i < DN; ++i) d1 += lqn[i] * lkn[i];
    for (int i = 0; i < DR; ++i) d2 += lqr[i] * lkr[i];
    outp[0] = __expf(d1) - __expf(d2) + LAM_INIT;
  }
}

__global__ void rope_q(uint16_t* __restrict__ q, const float* __restrict__ cs,
                       const float* __restrict__ sn){
  int idx = blockIdx.x*256 + threadIdx.x;          // SEQ*NH*32
  int j = idx & 31, hh = (idx>>5) & 15, s = idx >> 9;
  uint16_t* p = q + (size_t)s*(NH*QKH) + hh*QKH + DN + 2*j;
  float xr = bfu(p[0]), xi = bfu(p[1]);
  float c = cs[s*32+j], si = sn[s*32+j];
  p[0] = f2bf(xr*c - xi*si);
  p[1] = f2bf(xr*si + xi*c);
}

// rope'd k_pe -> kfull[h][t][128..192)
__global__ void rope_k(const uint16_t* __restrict__ kvf, const float* __restrict__ cs,
                       const float* __restrict__ sn, uint16_t* __restrict__ kfull){
  int idx = blockIdx.x*256 + threadIdx.x;          // NH*SEQ*32
  int j = idx & 31, t = (idx>>5) & 2047, hh = idx >> 16;
  float xr = bfu(kvf[(size_t)t*KVPAD + KVLR + 2*j]);
  float xi = bfu(kvf[(size_t)t*KVPAD + KVLR + 2*j + 1]);
  float c = cs[t*32+j], si = sn[t*32+j];
  uint16_t* p = kfull + ((size_t)hh*SEQ + t)*QKH + DN + 2*j;
  p[0] = f2bf(xr*c - xi*si);
  p[1] = f2bf(xr*si + xi*c);
}

// ---------------- attention ----------------
// Block = (q-chunk of 16 rows, head), 4 waves. Waves split the kv-tile range
// (wave w takes tiles i ≡ w mod 4), each with private (m,l,O1,O2); partials
// tree-combined through LDS at the end (exact online-softmax merge).
// __launch_bounds__(256,4): cap 128 VGPR (round-6 loop's natural allocation)
// -> 4 waves/SIMD, 4 blocks/CU. NOT waves_per_eu(4) (round-7: pinned 64, spilled).
__global__ __launch_bounds__(256, 4)
void attn_kernel(
    const uint16_t* __restrict__ q,     // [SEQ][NH*QKH]
    const uint16_t* __restrict__ kf,    // [NH][SEQ][QKH]
    const uint16_t* __restrict__ vt,    // [NH][DV][SEQ]
    const float* __restrict__ lamp,
    uint16_t* __restrict__ o)           // [SEQ][NH*DV]
{
  __shared__ __align__(16) uint16_t P_lds[4][4][16*PSTR];   // [wave][slice]
  __shared__ float R_lds[2][64*41];                          // combine buffers
  const int b  = blockIdx.x;
  const int h  = b & 15;
  const int c  = b >> 4;               // 0..127
  const int wid  = threadIdx.x >> 6;
  const int lane = threadIdx.x & 63;
  const int l15 = lane & 15;
  const int lhi = lane >> 4;
  const int subrow = lhi * 4;
  const int qrow0 = c * 16;
  const int kend  = qrow0 + 16;        // causal kv extent
  const float lam = lamp[0];

  bf16x8 qf[6];
  {
    const uint16_t* qbase = q + (size_t)(qrow0 + l15)*(NH*QKH) + h*QKH + lhi*8;
#pragma unroll
    for (int kb = 0; kb < 6; ++kb) qf[kb] = ldfrag(qbase + kb*32);
  }
  f32x4 O1[8] = {}, O2[8] = {};
  float m1[4], m2[4], l1[4], l2[4];
#pragma unroll
  for (int r = 0; r < 4; ++r) { m1[r] = m2[r] = -1e30f; l1[r] = l2[r] = 0.f; }

  const uint16_t* kbase = kf + (size_t)h*SEQ*QKH;
  const uint16_t* vbase = vt + (size_t)h*DV*SEQ;

  auto loadK = [&](bf16x8 (&k0)[6], bf16x8 (&k1)[6], int t0){
    const uint16_t* kp0 = kbase + (size_t)(t0 + l15)*QKH + lhi*8;
    const uint16_t* kp1 = kp0 + (size_t)16*QKH;
#pragma unroll
    for (int kb = 0; kb < 6; ++kb) { k0[kb] = ldfrag(kp0 + kb*32); k1[kb] = ldfrag(kp1 + kb*32); }
  };
  auto loadV = [&](bf16x8 (&vf)[8], int t0){
#pragma unroll
    for (int n = 0; n < 8; ++n) vf[n] = ldfrag(vbase + (size_t)(n*16 + l15)*SEQ + t0 + lhi*8);
  };
  auto qk = [&](bf16x8 (&k0)[6], bf16x8 (&k1)[6], f32x4 (&s1)[2], f32x4 (&s2)[2]){
    __builtin_amdgcn_s_setprio(1);
#pragma unroll
    for (int kb = 0; kb < 3; ++kb) { s1[0] = MFMA16(qf[kb], k0[kb], s1[0]); s1[1] = MFMA16(qf[kb], k1[kb], s1[1]); }
#pragma unroll
    for (int kb = 3; kb < 6; ++kb) { s2[0] = MFMA16(qf[kb], k0[kb], s2[0]); s2[1] = MFMA16(qf[kb], k1[kb], s2[1]); }
    __builtin_amdgcn_s_setprio(0);
  };
  auto smax = [&](f32x4 (&s1)[2], f32x4 (&s2)[2], int t0, bool MASKED,
                  uint16_t* pa, uint16_t* pb){
#pragma unroll
    for (int half = 0; half < 2; ++half)
#pragma unroll
      for (int r = 0; r < 4; ++r) {
        float v1 = fminf(fmaxf(s1[half][r]*SCALE_F, -100.f), 100.f);
        float v2 = fminf(fmaxf(s2[half][r]*SCALE_F, -100.f), 100.f);
        if (MASKED && (t0 + half*16 + l15 > qrow0 + subrow + r)) { v1 = -1e30f; v2 = -1e30f; }
        s1[half][r] = v1; s2[half][r] = v2;
      }
    float t1[4], t2[4];
#pragma unroll
    for (int r = 0; r < 4; ++r) { t1[r] = fmaxf(s1[0][r], s1[1][r]); t2[r] = fmaxf(s2[0][r], s2[1][r]); }
#pragma unroll
    for (int off = 1; off < 16; off <<= 1)
#pragma unroll
      for (int r = 0; r < 4; ++r) {
        t1[r] = fmaxf(t1[r], __shfl_xor(t1[r], off, 64));
        t2[r] = fmaxf(t2[r], __shfl_xor(t2[r], off, 64));
      }
    bool ok1 = (t1[0] <= m1[0]+DTHR) && (t1[1] <= m1[1]+DTHR) && (t1[2] <= m1[2]+DTHR) && (t1[3] <= m1[3]+DTHR);
    if (!__all(ok1)) {
#pragma unroll
      for (int r = 0; r < 4; ++r) {
        float mn = fmaxf(m1[r], t1[r]);
        float cr = __expf(m1[r] - mn);
        m1[r] = mn; l1[r] *= cr;
#pragma unroll
        for (int n = 0; n < 8; ++n) O1[n][r] *= cr;
      }
    }
    bool ok2 = (t2[0] <= m2[0]+DTHR) && (t2[1] <= m2[1]+DTHR) && (t2[2] <= m2[2]+DTHR) && (t2[3] <= m2[3]+DTHR);
    if (!__all(ok2)) {
#pragma unroll
      for (int r = 0; r < 4; ++r) {
        float mn = fmaxf(m2[r], t2[r]);
        float cr = __expf(m2[r] - mn);
        m2[r] = mn; l2[r] *= cr;
#pragma unroll
        for (int n = 0; n < 8; ++n) O2[n][r] *= cr;
      }
    }
    float rs1[4], rs2[4];
#pragma unroll
    for (int r = 0; r < 4; ++r) {
      float p10 = __expf(s1[0][r] - m1[r]), p11 = __expf(s1[1][r] - m1[r]);
      float p20 = __expf(s2[0][r] - m2[r]), p21 = __expf(s2[1][r] - m2[r]);
      pa[(subrow + r)*PSTR +      l15] = f2bf(p10);
      pa[(subrow + r)*PSTR + 16 + l15] = f2bf(p11);
      pb[(subrow + r)*PSTR +      l15] = f2bf(p20);
      pb[(subrow + r)*PSTR + 16 + l15] = f2bf(p21);
      rs1[r] = p10 + p11; rs2[r] = p20 + p21;
    }
#pragma unroll
    for (int off = 1; off < 16; off <<= 1)
#pragma unroll
      for (int r = 0; r < 4; ++r) {
        rs1[r] += __shfl_xor(rs1[r], off, 64);
        rs2[r] += __shfl_xor(rs2[r], off, 64);
      }
#pragma unroll
    for (int r = 0; r < 4; ++r) { l1[r] += rs1[r]; l2[r] += rs2[r]; }
  };
  auto pv = [&](bf16x8 (&vf)[8], const uint16_t* pa, const uint16_t* pb){
    bf16x8 pf0 = ldfrag(&pa[l15*PSTR + lhi*8]);
    bf16x8 pf1 = ldfrag(&pb[l15*PSTR + lhi*8]);
    __builtin_amdgcn_s_setprio(1);
#pragma unroll
    for (int n = 0; n < 8; ++n) {
      O1[n] = MFMA16(pf0, vf[n], O1[n]);
      O2[n] = MFMA16(pf1, vf[n], O2[n]);
    }
    __builtin_amdgcn_s_setprio(0);
  };

  uint16_t* plA0 = &P_lds[wid][0][0]; uint16_t* plA1 = &P_lds[wid][1][0];
  uint16_t* plB0 = &P_lds[wid][2][0]; uint16_t* plB1 = &P_lds[wid][3][0];

  const int n_tiles = (kend + 31) >> 5;
  const int nm = n_tiles - 1;          // index of the masked (diagonal) tile

  bf16x8 kr0[6], kr1[6], vfa[8], vfb[8];
  // paired unmasked tiles for this wave (indices wid, wid+4, ...)
  int i = wid;
  for (; i + 4 < nm; i += 8) {
    const int ta = i*32, tb = (i+4)*32;
    loadK(kr0, kr1, ta);
    loadV(vfa, ta);
    f32x4 sA1[2] = {}, sA2[2] = {};
    qk(kr0, kr1, sA1, sA2);
    loadK(kr0, kr1, tb);
    smax(sA1, sA2, ta, false, plA0, plA1);
    f32x4 sB1[2] = {}, sB2[2] = {};
    qk(kr0, kr1, sB1, sB2);
    loadV(vfb, tb);
    smax(sB1, sB2, tb, false, plB0, plB1);
    asm volatile("s_waitcnt lgkmcnt(0)" ::: "memory");
    __builtin_amdgcn_sched_barrier(0);
    pv(vfa, plA0, plA1);
    pv(vfb, plB0, plB1);
  }
  if (i < nm) {
    loadK(kr0, kr1, i*32);
    loadV(vfa, i*32);
    f32x4 s1[2] = {}, s2[2] = {};
    qk(kr0, kr1, s1, s2);
    smax(s1, s2, i*32, false, plA0, plA1);
    asm volatile("s_waitcnt lgkmcnt(0)" ::: "memory");
    __builtin_amdgcn_sched_barrier(0);
    pv(vfa, plA0, plA1);
  }
  if ((nm & 3) == wid) {
    loadK(kr0, kr1, nm*32);
    loadV(vfa, nm*32);
    f32x4 s1[2] = {}, s2[2] = {};
    qk(kr0, kr1, s1, s2);
    smax(s1, s2, nm*32, true, plA0, plA1);
    asm volatile("s_waitcnt lgkmcnt(0)" ::: "memory");
    __builtin_amdgcn_sched_barrier(0);
    pv(vfa, plA0, plA1);
  }

  // ---- cross-wave combine (exact online-softmax merge), tree: (2,3)->(0,1)->(0)
  auto write_state = [&](float* buf, const float* mm, const float* ll, const f32x4* O){
    float* p = buf + lane*41;
#pragma unroll
    for (int r = 0; r < 4; ++r) { p[r] = mm[r]; p[4+r] = ll[r]; }
#pragma unroll
    for (int n = 0; n < 8; ++n)
#pragma unroll
      for (int r = 0; r < 4; ++r) p[8 + n*4 + r] = O[n][r];
  };
  auto merge_state = [&](const float* buf, float* mm, float* ll, f32x4* O){
    const float* p = buf + lane*41;
    float ca[4], cb[4];
#pragma unroll
    for (int r = 0; r < 4; ++r) {
      float mo = p[r], lo = p[4+r];
      float mn = fmaxf(mm[r], mo);
      ca[r] = __expf(mm[r] - mn); cb[r] = __expf(mo - mn);
      mm[r] = mn; ll[r] = ll[r]*ca[r] + lo*cb[r];
    }
#pragma unroll
    for (int n = 0; n < 8; ++n)
#pragma unroll
      for (int r = 0; r < 4; ++r) O[n][r] = O[n][r]*ca[r] + p[8 + n*4 + r]*cb[r];
  };

  if (wid >= 2) write_state(R_lds[wid-2], m1, l1, O1);
  __syncthreads();
  if (wid < 2)  merge_state(R_lds[wid], m1, l1, O1);
  __syncthreads();
  if (wid >= 2) write_state(R_lds[wid-2], m2, l2, O2);
  __syncthreads();
  if (wid < 2)  merge_state(R_lds[wid], m2, l2, O2);
  __syncthreads();
  if (wid == 1) { write_state(R_lds[0], m1, l1, O1); write_state(R_lds[1], m2, l2, O2); }
  __syncthreads();
  if (wid == 0) {
    merge_state(R_lds[0], m1, l1, O1);
    merge_state(R_lds[1], m2, l2, O2);
    // epilogue: (O1/l1 - lam*O2/l2) * (1-lambda_init)
#pragma unroll
    for (int r = 0; r < 4; ++r) {
      float inv1 = 1.f / l1[r], inv2 = lam / l2[r];
#pragma unroll
      for (int n = 0; n < 8; ++n) {
        float val = (O1[n][r]*inv1 - O2[n][r]*inv2) * C1F;
        o[(size_t)(qrow0 + subrow + r)*(NH*DV) + h*DV + n*16 + l15] = f2bf(val);
      }
    }
  }
}

// ---------------- launch ----------------
extern "C" void kernel_launch(void* const* d_in, const int* in_sizes, int n_in,
                              void* d_out, int out_size, void* d_ws, size_t ws_size,
                              hipStream_t stream)
{
  const float* x     = (const float*)d_in[0];
  const float* wq_a  = (const float*)d_in[1];
  const float* wq_b  = (const float*)d_in[2];
  const float* wkv_a = (const float*)d_in[3];
  const float* wkv_b = (const float*)d_in[4];
  const float* wo    = (const float*)d_in[5];
  const float* lqn   = (const float*)d_in[6];
  const float* lqr   = (const float*)d_in[7];
  const float* lkn   = (const float*)d_in[8];
  const float* lkr   = (const float*)d_in[9];
  const float* fcos  = (const float*)d_in[10];
  const float* fsin  = (const float*)d_in[11];

  char* ws = (char*)d_ws;
  size_t off = 0;
  float*    lam    = (float*)(ws + off);  off += 256;
  uint16_t* xb     = (uint16_t*)(ws + off); off += (size_t)DIMM*DIMM*2;
  uint16_t* wqab   = (uint16_t*)(ws + off); off += (size_t)QLR*DIMM*2;
  uint16_t* wqbb   = (uint16_t*)(ws + off); off += (size_t)NH*QKH*QLR*2;
  uint16_t* wkvap  = (uint16_t*)(ws + off); off += (size_t)KVPAD*DIMM*2;
  uint16_t* wkvbb  = (uint16_t*)(ws + off); off += (size_t)4096*KVLR*2;
  uint16_t* wob    = (uint16_t*)(ws + off); off += (size_t)DIMM*DIMM*2;
  uint16_t* qlat   = (uint16_t*)(ws + off); off += (size_t)SEQ*QLR*2;
  uint16_t* qbuf   = (uint16_t*)(ws + off); off += (size_t)SEQ*NH*QKH*2;
  uint16_t* kvfull = (uint16_t*)(ws + off); off += (size_t)SEQ*KVPAD*2;
  uint16_t* kfull  = (uint16_t*)(ws + off); off += (size_t)NH*SEQ*QKH*2;
  uint16_t* vtb    = (uint16_t*)(ws + off); off += (size_t)NH*DV*SEQ*2;
  uint16_t* attn   = (uint16_t*)(ws + off); off += (size_t)SEQ*NH*DV*2;

  lam_kernel<<<1, 64, 0, stream>>>(lqn, lqr, lkn, lkr, lam);
  cvt<<<2048, 256, 0, stream>>>(x, xb);
  cvt<<< 768, 256, 0, stream>>>(wq_a, wqab);
  cvt<<<1152, 256, 0, stream>>>(wq_b, wqbb);
  cvt<<<1024, 256, 0, stream>>>(wkv_b, wkvbb);
  cvt<<<2048, 256, 0, stream>>>(wo, wob);
  pad_wkva<<<5120, 256, 0, stream>>>(wkv_a, wkvap);

  // q_lat = x @ wq_a^T
  gemm_bt<<<dim3(16, 6), 256, 0, stream>>>(xb, DIMM, wqab, qlat, QLR, DIMM);
  // q = q_lat @ wq_b^T
  gemm_bt<<<dim3(16, 24), 256, 0, stream>>>(qlat, QLR, wqbb, qbuf, NH*QKH, QLR);
  rope_q<<<4096, 256, 0, stream>>>(qbuf, fcos, fsin);
  // kv_full = x @ wkv_a_pad^T
  gemm_bt<<<dim3(16, 5), 256, 0, stream>>>(xb, DIMM, wkvap, kvfull, KVPAD, DIMM);
  // kvb GEMM fused: k_nope -> kfull, V -> vtb^T
  gemm_kvb<<<dim3(16, 32), 256, 0, stream>>>(kvfull, KVPAD, wkvbb, kfull, vtb, KVLR);
  rope_k<<<4096, 256, 0, stream>>>(kvfull, fcos, fsin, kfull);
  attn_kernel<<<2048, 256, 0, stream>>>(qbuf, kfull, vtb, lam, attn);
  // out = attn_out @ wo^T  (f32 output)
  gemm_bt<<<dim3(16, 16), 256, 0, stream>>>(attn, NH*DV, wob, (float*)d_out, DIMM, DIMM);
}

// Round 9
// 399.898 us; speedup vs baseline: 1.8263x; 1.7818x over previous
//
#include <hip/hip_runtime.h>
#include <stdint.h>

// ---------------- constants ----------------
#define SEQ   2048
#define NH    16
#define DIMM  2048
#define QLR   768
#define KVLR  512
#define DN    128
#define DR    64
#define DV    128
#define QKH   192           // DN + DR
#define KVPAD 640           // 576 padded to multiple of 128
#define SCALE_F 0.07216878364870323f   // 192^-0.5
#define LAM_INIT 0.5560582f            // 0.8 - 0.6*exp(-0.9)
#define C1F      0.4439418f            // 1 - LAM_INIT
#define PSTR  36            // P_lds row stride (elements) — conflict-breaking pad
#define DTHR  8.0f          // defer-max threshold (T13)

// ---------------- types ----------------
typedef __attribute__((ext_vector_type(8))) uint16_t u16x8;
typedef __attribute__((ext_vector_type(8))) __bf16   bf16x8;
typedef __attribute__((ext_vector_type(4))) float    f32x4;

#define MFMA16(a,b,c) __builtin_amdgcn_mfma_f32_16x16x32_bf16((a),(b),(c),0,0,0)

__device__ __forceinline__ uint16_t f2bf(float f){ uint32_t x; __builtin_memcpy(&x,&f,4); return (uint16_t)((x + 0x7FFFu + ((x>>16)&1u))>>16); }
__device__ __forceinline__ float bfu(uint16_t u){ return (float)__builtin_bit_cast(__bf16, u); }
__device__ __forceinline__ bf16x8 ldfrag(const uint16_t* p){ return __builtin_bit_cast(bf16x8, *(const u16x8*)p); }
__device__ __forceinline__ void gload_lds16(const uint16_t* g, uint16_t* l){
  __builtin_amdgcn_global_load_lds((const __attribute__((address_space(1))) void*)g,
                                   (__attribute__((address_space(3))) void*)l, 16, 0, 0);
}
__device__ __forceinline__ void stor(uint16_t* p, float v){ *p = f2bf(v); }
__device__ __forceinline__ void stor(float* p, float v){ *p = v; }

// ---------------- f32 -> bf16 converters ----------------
__global__ void cvt(const float* __restrict__ in, uint16_t* __restrict__ outp){
  int i = (blockIdx.x*256 + threadIdx.x)*8;
  float4 a = *(const float4*)(in + i);
  float4 b = *(const float4*)(in + i + 4);
  u16x8 r;
  r[0]=f2bf(a.x); r[1]=f2bf(a.y); r[2]=f2bf(a.z); r[3]=f2bf(a.w);
  r[4]=f2bf(b.x); r[5]=f2bf(b.y); r[6]=f2bf(b.z); r[7]=f2bf(b.w);
  *(u16x8*)(outp + i) = r;
}

// wkv_a f32 [576][2048] -> bf16 [640][2048] zero-padded
__global__ void pad_wkva(const float* __restrict__ in, uint16_t* __restrict__ outp){
  int idx = blockIdx.x*256 + threadIdx.x;          // KVPAD*DIMM
  int n = idx >> 11;
  outp[idx] = (n < 576) ? f2bf(in[idx]) : (uint16_t)0;
}

// ---------------- GEMM: C[M][N] = A[M][K] (lda) * B[N][K]^T, bf16 in, f32 acc ----
// 128x128 tile, 4 waves (2x2 of 64x64), BK=32, global_load_lds staging.
template <typename OT>
__global__ __launch_bounds__(256) void gemm_bt(const uint16_t* __restrict__ A, int lda,
                                               const uint16_t* __restrict__ B,
                                               OT* __restrict__ C, int ldc, int K)
{
  __shared__ __align__(16) uint16_t As[128*32];
  __shared__ __align__(16) uint16_t Bs[128*32];
  const int tid  = threadIdx.x;
  const int wid  = tid >> 6;
  const int lane = tid & 63;
  const int wr   = (wid >> 1) * 64;
  const int wc   = (wid & 1) * 64;
  const int srow = lane >> 2;
  const int scol = (lane & 3) * 8;
  const uint16_t* Abase = A + (size_t)(blockIdx.x * 128) * lda;
  const uint16_t* Bbase = B + (size_t)(blockIdx.y * 128) * K;
  f32x4 acc[4][4] = {};
  for (int k0 = 0; k0 < K; k0 += 32) {
    __syncthreads();
#pragma unroll
    for (int c = 0; c < 2; ++c) {
      int r = (wid*2 + c)*16 + srow;
      gload_lds16(Abase + (size_t)r*lda + k0 + scol, &As[(wid*2 + c)*512]);
      gload_lds16(Bbase + (size_t)r*K   + k0 + scol, &Bs[(wid*2 + c)*512]);
    }
    __syncthreads();
    bf16x8 af[4], bfr[4];
#pragma unroll
    for (int m = 0; m < 4; ++m)
      af[m] = ldfrag(&As[(wr + m*16 + (lane&15))*32 + ((lane>>4)*8)]);
#pragma unroll
    for (int n = 0; n < 4; ++n)
      bfr[n] = ldfrag(&Bs[(wc + n*16 + (lane&15))*32 + ((lane>>4)*8)]);
#pragma unroll
    for (int m = 0; m < 4; ++m)
#pragma unroll
      for (int n = 0; n < 4; ++n)
        acc[m][n] = MFMA16(af[m], bfr[n], acc[m][n]);
  }
  const int rbase = blockIdx.x*128 + wr + ((lane>>4)<<2);
  const int cbase = blockIdx.y*128 + wc + (lane&15);
#pragma unroll
  for (int m = 0; m < 4; ++m)
#pragma unroll
    for (int n = 0; n < 4; ++n)
#pragma unroll
      for (int r = 0; r < 4; ++r)
        stor(&C[(size_t)(rbase + m*16 + r)*ldc + cbase + n*16], acc[m][n][r]);
}

// ---- kvb GEMM with fused scatter epilogue: writes k_nope into kfull and V into vtb^T
__global__ __launch_bounds__(256) void gemm_kvb(const uint16_t* __restrict__ A, int lda,
                                                const uint16_t* __restrict__ B,
                                                uint16_t* __restrict__ kfull,
                                                uint16_t* __restrict__ vtb, int K)
{
  __shared__ __align__(16) uint16_t As[128*32];
  __shared__ __align__(16) uint16_t Bs[128*32];
  const int tid  = threadIdx.x;
  const int wid  = tid >> 6;
  const int lane = tid & 63;
  const int wr   = (wid >> 1) * 64;
  const int wc   = (wid & 1) * 64;
  const int srow = lane >> 2;
  const int scol = (lane & 3) * 8;
  const uint16_t* Abase = A + (size_t)(blockIdx.x * 128) * lda;
  const uint16_t* Bbase = B + (size_t)(blockIdx.y * 128) * K;
  f32x4 acc[4][4] = {};
  for (int k0 = 0; k0 < K; k0 += 32) {
    __syncthreads();
#pragma unroll
    for (int c = 0; c < 2; ++c) {
      int r = (wid*2 + c)*16 + srow;
      gload_lds16(Abase + (size_t)r*lda + k0 + scol, &As[(wid*2 + c)*512]);
      gload_lds16(Bbase + (size_t)r*K   + k0 + scol, &Bs[(wid*2 + c)*512]);
    }
    __syncthreads();
    bf16x8 af[4], bfr[4];
#pragma unroll
    for (int m = 0; m < 4; ++m)
      af[m] = ldfrag(&As[(wr + m*16 + (lane&15))*32 + ((lane>>4)*8)]);
#pragma unroll
    for (int n = 0; n < 4; ++n)
      bfr[n] = ldfrag(&Bs[(wc + n*16 + (lane&15))*32 + ((lane>>4)*8)]);
#pragma unroll
    for (int m = 0; m < 4; ++m)
#pragma unroll
      for (int n = 0; n < 4; ++n)
        acc[m][n] = MFMA16(af[m], bfr[n], acc[m][n]);
  }
  const int rbase = blockIdx.x*128 + wr + ((lane>>4)<<2);
  const int cbase = blockIdx.y*128 + wc + (lane&15);
#pragma unroll
  for (int m = 0; m < 4; ++m)
#pragma unroll
    for (int n = 0; n < 4; ++n) {
      const int gcol = cbase + n*16;
      const int hh = gcol >> 8, d = gcol & 255;
#pragma unroll
      for (int r = 0; r < 4; ++r) {
        const int t = rbase + m*16 + r;
        if (d < DN) kfull[((size_t)hh*SEQ + t)*QKH + d] = f2bf(acc[m][n][r]);
        else        vtb[((size_t)hh*DV + (d - DN))*SEQ + t] = f2bf(acc[m][n][r]);
      }
    }
}

// ---------------- small kernels ----------------
__global__ void lam_kernel(const float* lqn, const float* lqr,
                           const float* lkn, const float* lkr, float* outp){
  if (threadIdx.x == 0 && blockIdx.x == 0) {
    float d1 = 0.f, d2 = 0.f;
    for (int i = 0; i < DN; ++i) d1 += lqn[i] * lkn[i];
    for (int i = 0; i < DR; ++i) d2 += lqr[i] * lkr[i];
    outp[0] = __expf(d1) - __expf(d2) + LAM_INIT;
  }
}

__global__ void rope_q(uint16_t* __restrict__ q, const float* __restrict__ cs,
                       const float* __restrict__ sn){
  int idx = blockIdx.x*256 + threadIdx.x;          // SEQ*NH*32
  int j = idx & 31, hh = (idx>>5) & 15, s = idx >> 9;
  uint16_t* p = q + (size_t)s*(NH*QKH) + hh*QKH + DN + 2*j;
  float xr = bfu(p[0]), xi = bfu(p[1]);
  float c = cs[s*32+j], si = sn[s*32+j];
  p[0] = f2bf(xr*c - xi*si);
  p[1] = f2bf(xr*si + xi*c);
}

// rope'd k_pe -> kfull[h][t][128..192)
__global__ void rope_k(const uint16_t* __restrict__ kvf, const float* __restrict__ cs,
                       const float* __restrict__ sn, uint16_t* __restrict__ kfull){
  int idx = blockIdx.x*256 + threadIdx.x;          // NH*SEQ*32
  int j = idx & 31, t = (idx>>5) & 2047, hh = idx >> 16;
  float xr = bfu(kvf[(size_t)t*KVPAD + KVLR + 2*j]);
  float xi = bfu(kvf[(size_t)t*KVPAD + KVLR + 2*j + 1]);
  float c = cs[t*32+j], si = sn[t*32+j];
  uint16_t* p = kfull + ((size_t)hh*SEQ + t)*QKH + DN + 2*j;
  p[0] = f2bf(xr*c - xi*si);
  p[1] = f2bf(xr*si + xi*c);
}

// ---------------- attention ----------------
// Block = (q-chunk of 16 rows, head), 4 waves. Waves split the kv-tile range
// (wave w takes tiles i ≡ w mod 4), each with private (m,l,O1,O2); partials
// tree-combined through LDS at the end (exact online-softmax merge).
// VGPR pin: amdgpu_waves_per_eu(2) -> compiler cap 128 on this toolchain
// (r6: capped 128, zero spill). NOT (256,4)/waves_per_eu(4): cap 64 -> 2GB spill
// (r7/r8). Hardware occupancy from actual 128 VGPR: 4 waves/EU = 4 blocks/CU.
__global__ __launch_bounds__(256) __attribute__((amdgpu_waves_per_eu(2)))
void attn_kernel(
    const uint16_t* __restrict__ q,     // [SEQ][NH*QKH]
    const uint16_t* __restrict__ kf,    // [NH][SEQ][QKH]
    const uint16_t* __restrict__ vt,    // [NH][DV][SEQ]
    const float* __restrict__ lamp,
    uint16_t* __restrict__ o)           // [SEQ][NH*DV]
{
  __shared__ __align__(16) uint16_t P_lds[4][4][16*PSTR];   // [wave][slice]
  __shared__ float R_lds[2][64*41];                          // combine buffers
  const int b  = blockIdx.x;
  const int h  = b & 15;
  const int c  = b >> 4;               // 0..127
  const int wid  = threadIdx.x >> 6;
  const int lane = threadIdx.x & 63;
  const int l15 = lane & 15;
  const int lhi = lane >> 4;
  const int subrow = lhi * 4;
  const int qrow0 = c * 16;
  const int kend  = qrow0 + 16;        // causal kv extent
  const float lam = lamp[0];

  bf16x8 qf[6];
  {
    const uint16_t* qbase = q + (size_t)(qrow0 + l15)*(NH*QKH) + h*QKH + lhi*8;
#pragma unroll
    for (int kb = 0; kb < 6; ++kb) qf[kb] = ldfrag(qbase + kb*32);
  }
  f32x4 O1[8] = {}, O2[8] = {};
  float m1[4], m2[4], l1[4], l2[4];
#pragma unroll
  for (int r = 0; r < 4; ++r) { m1[r] = m2[r] = -1e30f; l1[r] = l2[r] = 0.f; }

  const uint16_t* kbase = kf + (size_t)h*SEQ*QKH;
  const uint16_t* vbase = vt + (size_t)h*DV*SEQ;

  auto loadK = [&](bf16x8 (&k0)[6], bf16x8 (&k1)[6], int t0){
    const uint16_t* kp0 = kbase + (size_t)(t0 + l15)*QKH + lhi*8;
    const uint16_t* kp1 = kp0 + (size_t)16*QKH;
#pragma unroll
    for (int kb = 0; kb < 6; ++kb) { k0[kb] = ldfrag(kp0 + kb*32); k1[kb] = ldfrag(kp1 + kb*32); }
  };
  auto loadV = [&](bf16x8 (&vf)[8], int t0){
#pragma unroll
    for (int n = 0; n < 8; ++n) vf[n] = ldfrag(vbase + (size_t)(n*16 + l15)*SEQ + t0 + lhi*8);
  };
  auto qk = [&](bf16x8 (&k0)[6], bf16x8 (&k1)[6], f32x4 (&s1)[2], f32x4 (&s2)[2]){
    __builtin_amdgcn_s_setprio(1);
#pragma unroll
    for (int kb = 0; kb < 3; ++kb) { s1[0] = MFMA16(qf[kb], k0[kb], s1[0]); s1[1] = MFMA16(qf[kb], k1[kb], s1[1]); }
#pragma unroll
    for (int kb = 3; kb < 6; ++kb) { s2[0] = MFMA16(qf[kb], k0[kb], s2[0]); s2[1] = MFMA16(qf[kb], k1[kb], s2[1]); }
    __builtin_amdgcn_s_setprio(0);
  };
  auto smax = [&](f32x4 (&s1)[2], f32x4 (&s2)[2], int t0, bool MASKED,
                  uint16_t* pa, uint16_t* pb){
#pragma unroll
    for (int half = 0; half < 2; ++half)
#pragma unroll
      for (int r = 0; r < 4; ++r) {
        float v1 = fminf(fmaxf(s1[half][r]*SCALE_F, -100.f), 100.f);
        float v2 = fminf(fmaxf(s2[half][r]*SCALE_F, -100.f), 100.f);
        if (MASKED && (t0 + half*16 + l15 > qrow0 + subrow + r)) { v1 = -1e30f; v2 = -1e30f; }
        s1[half][r] = v1; s2[half][r] = v2;
      }
    float t1[4], t2[4];
#pragma unroll
    for (int r = 0; r < 4; ++r) { t1[r] = fmaxf(s1[0][r], s1[1][r]); t2[r] = fmaxf(s2[0][r], s2[1][r]); }
#pragma unroll
    for (int off = 1; off < 16; off <<= 1)
#pragma unroll
      for (int r = 0; r < 4; ++r) {
        t1[r] = fmaxf(t1[r], __shfl_xor(t1[r], off, 64));
        t2[r] = fmaxf(t2[r], __shfl_xor(t2[r], off, 64));
      }
    bool ok1 = (t1[0] <= m1[0]+DTHR) && (t1[1] <= m1[1]+DTHR) && (t1[2] <= m1[2]+DTHR) && (t1[3] <= m1[3]+DTHR);
    if (!__all(ok1)) {
#pragma unroll
      for (int r = 0; r < 4; ++r) {
        float mn = fmaxf(m1[r], t1[r]);
        float cr = __expf(m1[r] - mn);
        m1[r] = mn; l1[r] *= cr;
#pragma unroll
        for (int n = 0; n < 8; ++n) O1[n][r] *= cr;
      }
    }
    bool ok2 = (t2[0] <= m2[0]+DTHR) && (t2[1] <= m2[1]+DTHR) && (t2[2] <= m2[2]+DTHR) && (t2[3] <= m2[3]+DTHR);
    if (!__all(ok2)) {
#pragma unroll
      for (int r = 0; r < 4; ++r) {
        float mn = fmaxf(m2[r], t2[r]);
        float cr = __expf(m2[r] - mn);
        m2[r] = mn; l2[r] *= cr;
#pragma unroll
        for (int n = 0; n < 8; ++n) O2[n][r] *= cr;
      }
    }
    float rs1[4], rs2[4];
#pragma unroll
    for (int r = 0; r < 4; ++r) {
      float p10 = __expf(s1[0][r] - m1[r]), p11 = __expf(s1[1][r] - m1[r]);
      float p20 = __expf(s2[0][r] - m2[r]), p21 = __expf(s2[1][r] - m2[r]);
      pa[(subrow + r)*PSTR +      l15] = f2bf(p10);
      pa[(subrow + r)*PSTR + 16 + l15] = f2bf(p11);
      pb[(subrow + r)*PSTR +      l15] = f2bf(p20);
      pb[(subrow + r)*PSTR + 16 + l15] = f2bf(p21);
      rs1[r] = p10 + p11; rs2[r] = p20 + p21;
    }
#pragma unroll
    for (int off = 1; off < 16; off <<= 1)
#pragma unroll
      for (int r = 0; r < 4; ++r) {
        rs1[r] += __shfl_xor(rs1[r], off, 64);
        rs2[r] += __shfl_xor(rs2[r], off, 64);
      }
#pragma unroll
    for (int r = 0; r < 4; ++r) { l1[r] += rs1[r]; l2[r] += rs2[r]; }
  };
  auto pv = [&](bf16x8 (&vf)[8], const uint16_t* pa, const uint16_t* pb){
    bf16x8 pf0 = ldfrag(&pa[l15*PSTR + lhi*8]);
    bf16x8 pf1 = ldfrag(&pb[l15*PSTR + lhi*8]);
    __builtin_amdgcn_s_setprio(1);
#pragma unroll
    for (int n = 0; n < 8; ++n) {
      O1[n] = MFMA16(pf0, vf[n], O1[n]);
      O2[n] = MFMA16(pf1, vf[n], O2[n]);
    }
    __builtin_amdgcn_s_setprio(0);
  };

  uint16_t* plA0 = &P_lds[wid][0][0]; uint16_t* plA1 = &P_lds[wid][1][0];
  uint16_t* plB0 = &P_lds[wid][2][0]; uint16_t* plB1 = &P_lds[wid][3][0];

  const int n_tiles = (kend + 31) >> 5;
  const int nm = n_tiles - 1;          // index of the masked (diagonal) tile

  bf16x8 kr0[6], kr1[6], vfa[8], vfb[8];
  // paired unmasked tiles for this wave (indices wid, wid+4, ...)
  int i = wid;
  for (; i + 4 < nm; i += 8) {
    const int ta = i*32, tb = (i+4)*32;
    loadK(kr0, kr1, ta);
    loadV(vfa, ta);
    f32x4 sA1[2] = {}, sA2[2] = {};
    qk(kr0, kr1, sA1, sA2);
    loadK(kr0, kr1, tb);
    smax(sA1, sA2, ta, false, plA0, plA1);
    f32x4 sB1[2] = {}, sB2[2] = {};
    qk(kr0, kr1, sB1, sB2);
    loadV(vfb, tb);
    smax(sB1, sB2, tb, false, plB0, plB1);
    asm volatile("s_waitcnt lgkmcnt(0)" ::: "memory");
    __builtin_amdgcn_sched_barrier(0);
    pv(vfa, plA0, plA1);
    pv(vfb, plB0, plB1);
  }
  if (i < nm) {
    loadK(kr0, kr1, i*32);
    loadV(vfa, i*32);
    f32x4 s1[2] = {}, s2[2] = {};
    qk(kr0, kr1, s1, s2);
    smax(s1, s2, i*32, false, plA0, plA1);
    asm volatile("s_waitcnt lgkmcnt(0)" ::: "memory");
    __builtin_amdgcn_sched_barrier(0);
    pv(vfa, plA0, plA1);
  }
  if ((nm & 3) == wid) {
    loadK(kr0, kr1, nm*32);
    loadV(vfa, nm*32);
    f32x4 s1[2] = {}, s2[2] = {};
    qk(kr0, kr1, s1, s2);
    smax(s1, s2, nm*32, true, plA0, plA1);
    asm volatile("s_waitcnt lgkmcnt(0)" ::: "memory");
    __builtin_amdgcn_sched_barrier(0);
    pv(vfa, plA0, plA1);
  }

  // ---- cross-wave combine (exact online-softmax merge), tree: (2,3)->(0,1)->(0)
  auto write_state = [&](float* buf, const float* mm, const float* ll, const f32x4* O){
    float* p = buf + lane*41;
#pragma unroll
    for (int r = 0; r < 4; ++r) { p[r] = mm[r]; p[4+r] = ll[r]; }
#pragma unroll
    for (int n = 0; n < 8; ++n)
#pragma unroll
      for (int r = 0; r < 4; ++r) p[8 + n*4 + r] = O[n][r];
  };
  auto merge_state = [&](const float* buf, float* mm, float* ll, f32x4* O){
    const float* p = buf + lane*41;
    float ca[4], cb[4];
#pragma unroll
    for (int r = 0; r < 4; ++r) {
      float mo = p[r], lo = p[4+r];
      float mn = fmaxf(mm[r], mo);
      ca[r] = __expf(mm[r] - mn); cb[r] = __expf(mo - mn);
      mm[r] = mn; ll[r] = ll[r]*ca[r] + lo*cb[r];
    }
#pragma unroll
    for (int n = 0; n < 8; ++n)
#pragma unroll
      for (int r = 0; r < 4; ++r) O[n][r] = O[n][r]*ca[r] + p[8 + n*4 + r]*cb[r];
  };

  if (wid >= 2) write_state(R_lds[wid-2], m1, l1, O1);
  __syncthreads();
  if (wid < 2)  merge_state(R_lds[wid], m1, l1, O1);
  __syncthreads();
  if (wid >= 2) write_state(R_lds[wid-2], m2, l2, O2);
  __syncthreads();
  if (wid < 2)  merge_state(R_lds[wid], m2, l2, O2);
  __syncthreads();
  if (wid == 1) { write_state(R_lds[0], m1, l1, O1); write_state(R_lds[1], m2, l2, O2); }
  __syncthreads();
  if (wid == 0) {
    merge_state(R_lds[0], m1, l1, O1);
    merge_state(R_lds[1], m2, l2, O2);
    // epilogue: (O1/l1 - lam*O2/l2) * (1-lambda_init)
#pragma unroll
    for (int r = 0; r < 4; ++r) {
      float inv1 = 1.f / l1[r], inv2 = lam / l2[r];
#pragma unroll
      for (int n = 0; n < 8; ++n) {
        float val = (O1[n][r]*inv1 - O2[n][r]*inv2) * C1F;
        o[(size_t)(qrow0 + subrow + r)*(NH*DV) + h*DV + n*16 + l15] = f2bf(val);
      }
    }
  }
}

// ---------------- launch ----------------
extern "C" void kernel_launch(void* const* d_in, const int* in_sizes, int n_in,
                              void* d_out, int out_size, void* d_ws, size_t ws_size,
                              hipStream_t stream)
{
  const float* x     = (const float*)d_in[0];
  const float* wq_a  = (const float*)d_in[1];
  const float* wq_b  = (const float*)d_in[2];
  const float* wkv_a = (const float*)d_in[3];
  const float* wkv_b = (const float*)d_in[4];
  const float* wo    = (const float*)d_in[5];
  const float* lqn   = (const float*)d_in[6];
  const float* lqr   = (const float*)d_in[7];
  const float* lkn   = (const float*)d_in[8];
  const float* lkr   = (const float*)d_in[9];
  const float* fcos  = (const float*)d_in[10];
  const float* fsin  = (const float*)d_in[11];

  char* ws = (char*)d_ws;
  size_t off = 0;
  float*    lam    = (float*)(ws + off);  off += 256;
  uint16_t* xb     = (uint16_t*)(ws + off); off += (size_t)DIMM*DIMM*2;
  uint16_t* wqab   = (uint16_t*)(ws + off); off += (size_t)QLR*DIMM*2;
  uint16_t* wqbb   = (uint16_t*)(ws + off); off += (size_t)NH*QKH*QLR*2;
  uint16_t* wkvap  = (uint16_t*)(ws + off); off += (size_t)KVPAD*DIMM*2;
  uint16_t* wkvbb  = (uint16_t*)(ws + off); off += (size_t)4096*KVLR*2;
  uint16_t* wob    = (uint16_t*)(ws + off); off += (size_t)DIMM*DIMM*2;
  uint16_t* qlat   = (uint16_t*)(ws + off); off += (size_t)SEQ*QLR*2;
  uint16_t* qbuf   = (uint16_t*)(ws + off); off += (size_t)SEQ*NH*QKH*2;
  uint16_t* kvfull = (uint16_t*)(ws + off); off += (size_t)SEQ*KVPAD*2;
  uint16_t* kfull  = (uint16_t*)(ws + off); off += (size_t)NH*SEQ*QKH*2;
  uint16_t* vtb    = (uint16_t*)(ws + off); off += (size_t)NH*DV*SEQ*2;
  uint16_t* attn   = (uint16_t*)(ws + off); off += (size_t)SEQ*NH*DV*2;

  lam_kernel<<<1, 64, 0, stream>>>(lqn, lqr, lkn, lkr, lam);
  cvt<<<2048, 256, 0, stream>>>(x, xb);
  cvt<<< 768, 256, 0, stream>>>(wq_a, wqab);
  cvt<<<1152, 256, 0, stream>>>(wq_b, wqbb);
  cvt<<<1024, 256, 0, stream>>>(wkv_b, wkvbb);
  cvt<<<2048, 256, 0, stream>>>(wo, wob);
  pad_wkva<<<5120, 256, 0, stream>>>(wkv_a, wkvap);

  // q_lat = x @ wq_a^T
  gemm_bt<<<dim3(16, 6), 256, 0, stream>>>(xb, DIMM, wqab, qlat, QLR, DIMM);
  // q = q_lat @ wq_b^T
  gemm_bt<<<dim3(16, 24), 256, 0, stream>>>(qlat, QLR, wqbb, qbuf, NH*QKH, QLR);
  rope_q<<<4096, 256, 0, stream>>>(qbuf, fcos, fsin);
  // kv_full = x @ wkv_a_pad^T
  gemm_bt<<<dim3(16, 5), 256, 0, stream>>>(xb, DIMM, wkvap, kvfull, KVPAD, DIMM);
  // kvb GEMM fused: k_nope -> kfull, V -> vtb^T
  gemm_kvb<<<dim3(16, 32), 256, 0, stream>>>(kvfull, KVPAD, wkvbb, kfull, vtb, KVLR);
  rope_k<<<4096, 256, 0, stream>>>(kvfull, fcos, fsin, kfull);
  attn_kernel<<<2048, 256, 0, stream>>>(qbuf, kfull, vtb, lam, attn);
  // out = attn_out @ wo^T  (f32 output)
  gemm_bt<<<dim3(16, 16), 256, 0, stream>>>(attn, NH*DV, wob, (float*)d_out, DIMM, DIMM);
}